// Round 1
// baseline (114.401 us; speedup 1.0000x reference)
//
#include <hip/hip_runtime.h>
#include <math.h>

#define HID 128
#define CIN 64
#define NB 8
#define HD 128
#define WD 128
#define HW (HD*WD)   // 16384

// wcomp layout (in ws): Wd'[HID][CIN] | Wb'[HID][CIN] | bd'[HID] | bb'[HID]
// Wd' = W_delta . W_in, bd' = W_delta . b_in + b_delta  (same for B)

// =================== L1: upsample + weight-compose + (gamma==0 only) copy ===================
// blocks [0,512):    prior bilinear upsample (align_corners) + clip -> out1   (always)
// blocks [512,544):  composite weights Wd', Wb'                              (always, tiny)
// block  544:        composite biases bd', bb'                               (always, tiny)
// blocks [545,4641): out0 = x copy — ONLY when gamma==0 (gamma!=0: L4 writes out0 fully)
__global__ __launch_bounds__(256, 2) void head_kernel(const float* __restrict__ x,
                                                      const float* __restrict__ prior,
                                                      const float* __restrict__ W_in,
                                                      const float* __restrict__ b_in,
                                                      const float* __restrict__ W_delta,
                                                      const float* __restrict__ b_delta,
                                                      const float* __restrict__ W_B,
                                                      const float* __restrict__ b_B,
                                                      float* __restrict__ wcomp,
                                                      float* __restrict__ out0,
                                                      float* __restrict__ out1,
                                                      const float* __restrict__ gamma_p) {
    int bid = blockIdx.x;
    if (bid < 512) {
        int idx = bid * 256 + threadIdx.x;                 // 512*256 = 131072 = 8*128*128
        int b = idx >> 14;
        int rem = idx & 16383;
        int i = rem >> 7, j = rem & 127;
        const float scale = 63.0f / 127.0f;
        float ys = i * scale;
        float xs = j * scale;
        int y0 = (int)floorf(ys); int y1 = min(y0 + 1, 63);
        int x0 = (int)floorf(xs); int x1 = min(x0 + 1, 63);
        float wy = ys - (float)y0, wx = xs - (float)x0;
        const float* p = prior + b * 4096;
        float v00 = p[y0 * 64 + x0], v01 = p[y0 * 64 + x1];
        float v10 = p[y1 * 64 + x0], v11 = p[y1 * 64 + x1];
        float r0 = v00 * (1.f - wy) + v10 * wy;
        float r1 = v01 * (1.f - wy) + v11 * wy;
        float v = r0 * (1.f - wx) + r1 * wx;
        v = fminf(fmaxf(v, -1.f), 1.f);
        out1[idx] = v;
        return;
    }
    if (bid < 544) {
        // Wd'[o][c] = sum_h W_delta[o][h] * W_in[h][c]; same for Wb'
        int idx = (bid - 512) * 256 + threadIdx.x;         // [0, 8192) = HID*CIN
        int o = idx >> 6, c = idx & 63;
        float wd = 0.f, wb = 0.f;
        for (int h = 0; h < HID; ++h) {
            float wi = W_in[h * CIN + c];
            wd = fmaf(W_delta[o * HID + h], wi, wd);
            wb = fmaf(W_B[o * HID + h], wi, wb);
        }
        wcomp[o * CIN + c] = wd;
        wcomp[HID * CIN + o * CIN + c] = wb;
        return;
    }
    if (bid == 544) {
        int o = threadIdx.x;
        if (o < HID) {
            float sd = b_delta[o], sb = b_B[o];
            for (int h = 0; h < HID; ++h) {
                float bi = b_in[h];
                sd = fmaf(W_delta[o * HID + h], bi, sd);
                sb = fmaf(W_B[o * HID + h], bi, sb);
            }
            wcomp[2 * HID * CIN + o] = sd;
            wcomp[2 * HID * CIN + HID + o] = sb;
        }
        return;
    }
    // ---- copy region: gamma!=0 => out0 fully written by conv_out; skip ----
    if (gamma_p[0] != 0.f) return;
    int idx = ((bid - 545) * 256 + threadIdx.x) * 4;       // 4096 blocks * 256 * 4 = 4,194,304
    *(float4*)(out0 + idx) = *(const float4*)(x + idx);
    int idx2 = idx + 4194304;
    *(float4*)(out0 + idx2) = *(const float4*)(x + idx2);
}

// ======= L2: fused gate: feat/delta/B GEMMs all K=64 straight from x =======
// feat  = W_in  . x + b_in          (16 ch of HID per block)
// d_pre = Wd'   . x + bd' + lam*pu ; delta = softplus(d_pre)
// B_pre = Wb'   . x + bb'          ; Bk = B_pre*(1+alpha*pu)
// Abar = exp(delta * -exp(A)); bbuf = delta * Bk * feat
__global__ __launch_bounds__(256, 2) void gate_kernel(const float* __restrict__ x,
                                                      const float* __restrict__ pu,
                                                      const float* __restrict__ W_in,
                                                      const float* __restrict__ b_in,
                                                      const float* __restrict__ wcomp,
                                                      const float* __restrict__ lam_p,
                                                      const float* __restrict__ alpha_p,
                                                      const float* __restrict__ A,
                                                      float* __restrict__ Abar,
                                                      float* __restrict__ bbuf,
                                                      const float* __restrict__ gamma_p) {
    if (gamma_p[0] == 0.f) return;
    const float lam = lam_p[0], alpha = alpha_p[0];
    int bx = blockIdx.x;                                   // 16 spatial tiles of 1024 px
    int og = blockIdx.y;                                   // 8 groups of 16 channels
    int b  = blockIdx.z;
    int p0 = bx * 1024 + threadIdx.x * 4;
    const float* Wdp = wcomp;
    const float* Wbp = wcomp + HID * CIN;
    const float* bdp = wcomp + 2 * HID * CIN;
    const float* bbp = bdp + HID;

    __shared__ float sw[3][CIN][16];                       // [which][c][j], 12 KB
    for (int idx = threadIdx.x; idx < 3 * CIN * 16; idx += 256) {
        int w = idx >> 10;
        int rem = idx & 1023;
        int c = rem >> 4, j = rem & 15;
        int o = og * 16 + j;
        const float* src = (w == 0) ? W_in : (w == 1) ? Wdp : Wbp;
        sw[w][c][j] = src[o * CIN + c];
    }
    __syncthreads();

    float ai[16][4], ad[16][4], ab[16][4];
#pragma unroll
    for (int j = 0; j < 16; ++j)
#pragma unroll
        for (int k = 0; k < 4; ++k) { ai[j][k] = 0.f; ad[j][k] = 0.f; ab[j][k] = 0.f; }

    const float* xb = x + b * (CIN * HW) + p0;
    for (int c = 0; c < CIN; ++c) {
        float4 xv = *(const float4*)(xb + c * HW);
#pragma unroll
        for (int j = 0; j < 16; ++j) {
            float wi = sw[0][c][j];
            float wd = sw[1][c][j];
            float wb = sw[2][c][j];
            ai[j][0] = fmaf(wi, xv.x, ai[j][0]);
            ai[j][1] = fmaf(wi, xv.y, ai[j][1]);
            ai[j][2] = fmaf(wi, xv.z, ai[j][2]);
            ai[j][3] = fmaf(wi, xv.w, ai[j][3]);
            ad[j][0] = fmaf(wd, xv.x, ad[j][0]);
            ad[j][1] = fmaf(wd, xv.y, ad[j][1]);
            ad[j][2] = fmaf(wd, xv.z, ad[j][2]);
            ad[j][3] = fmaf(wd, xv.w, ad[j][3]);
            ab[j][0] = fmaf(wb, xv.x, ab[j][0]);
            ab[j][1] = fmaf(wb, xv.y, ab[j][1]);
            ab[j][2] = fmaf(wb, xv.z, ab[j][2]);
            ab[j][3] = fmaf(wb, xv.w, ab[j][3]);
        }
    }

    float4 pu4 = *(const float4*)(pu + b * HW + p0);
    float pus[4] = {pu4.x, pu4.y, pu4.z, pu4.w};
    int base = b * (HID * HW) + p0;
#pragma unroll
    for (int j = 0; j < 16; ++j) {
        int o = og * 16 + j;
        float bi = b_in[o], bd = bdp[o], bb2 = bbp[o];
        float nA = -expf(A[o]);
        float Ao[4], bo[4];
#pragma unroll
        for (int k = 0; k < 4; ++k) {
            float dv = ad[j][k] + bd + lam * pus[k];
            float d  = fmaxf(dv, 0.f) + log1pf(expf(-fabsf(dv)));   // softplus
            Ao[k] = expf(d * nA);
            float feat = ai[j][k] + bi;
            float Bk = (ab[j][k] + bb2) * (1.f + alpha * pus[k]);
            bo[k] = d * Bk * feat;
        }
        *(float4*)(Abar + base + o * HW) = make_float4(Ao[0], Ao[1], Ao[2], Ao[3]);
        *(float4*)(bbuf + base + o * HW) = make_float4(bo[0], bo[1], bo[2], bo[3]);
    }
}

// =================== L3: fused scans, single (h+v) sum output ===================
// One block per (b,c) plane. Phase 1: v-scan (thread per column) -> LDS.
// Phase 2: h-scan (wave-shuffle per row), add LDS v-result, write sum once.
__global__ __launch_bounds__(256) void scan_sum_kernel(const float* __restrict__ Abar,
                                                       const float* __restrict__ bbuf,
                                                       float* __restrict__ sum,
                                                       const float* __restrict__ gamma_p) {
    if (gamma_p[0] == 0.f) return;
    __shared__ float vres[HD * WD];                        // 64 KB
    int plane = blockIdx.x;                                // [0, NB*HID)
    const float* Ab = Abar + plane * HW;
    const float* Bb = bbuf + plane * HW;
    float* So = sum + plane * HW;
    int t = threadIdx.x;
    if (t < WD) {
        float P = 1.f, s = 0.f;
        for (int i = 0; i < HD; ++i) {
            int off = i * WD + t;
            float a  = Ab[off];
            float bv = Bb[off];
            P *= a;
            s += bv / fmaxf(P, 1e-8f);
            vres[off] = P * s;
        }
    }
    __syncthreads();
    int lane = t & 63, wv = t >> 6;
    for (int it = 0; it < 32; ++it) {
        int r = wv * 32 + it;
        int base = r * WD + lane * 2;
        float2 a2 = *(const float2*)(Ab + base);
        float2 b2 = *(const float2*)(Bb + base);
        float pa = a2.x, pb = a2.x * a2.y;
        float Lp = pb;
#pragma unroll
        for (int off = 1; off < 64; off <<= 1) {
            float tt = __shfl_up(Lp, off, 64);
            if (lane >= off) Lp *= tt;
        }
        float ep = __shfl_up(Lp, 1, 64);
        if (lane == 0) ep = 1.f;
        float P0 = ep * pa, P1 = ep * pb;
        float q0 = b2.x / fmaxf(P0, 1e-8f);
        float q1 = b2.y / fmaxf(P1, 1e-8f);
        float s0 = q0, s1 = q0 + q1;
        float Ls = s1;
#pragma unroll
        for (int off = 1; off < 64; off <<= 1) {
            float tt = __shfl_up(Ls, off, 64);
            if (lane >= off) Ls += tt;
        }
        float es = __shfl_up(Ls, 1, 64);
        if (lane == 0) es = 0.f;
        float h0 = P0 * (es + s0), h1 = P1 * (es + s1);
        *(float2*)(So + base) = make_float2(h0 + vres[base], h1 + vres[base + 1]);
    }
}

// ====== L4: out0 = x + gamma * (W_out . sum + b_out)  (gamma!=0 only) ======
__global__ __launch_bounds__(256, 2) void conv_out_kernel(const float* __restrict__ sum,
                                                          const float* __restrict__ x,
                                                          const float* __restrict__ W_out,
                                                          const float* __restrict__ b_out,
                                                          const float* __restrict__ gamma_p,
                                                          float* __restrict__ out0) {
    float g = gamma_p[0];
    if (g == 0.f) return;
    int bx = blockIdx.x;                                   // 16 spatial tiles
    int og = blockIdx.y;                                   // 4 groups of 16 out channels
    int b  = blockIdx.z;
    int p0 = bx * 1024 + threadIdx.x * 4;
    __shared__ float sw[HID][16];                          // [c][j], 8 KB
    for (int idx = threadIdx.x; idx < HID * 16; idx += 256) {
        int c = idx >> 4, j = idx & 15;
        sw[c][j] = W_out[(og * 16 + j) * HID + c];
    }
    __syncthreads();
    float acc[16][4];
#pragma unroll
    for (int j = 0; j < 16; ++j)
#pragma unroll
        for (int k = 0; k < 4; ++k) acc[j][k] = 0.f;
    const float* sb = sum + b * (HID * HW) + p0;
    for (int c = 0; c < HID; ++c) {
        float4 sv = *(const float4*)(sb + c * HW);
#pragma unroll
        for (int j = 0; j < 16; ++j) {
            float w = sw[c][j];
            acc[j][0] = fmaf(w, sv.x, acc[j][0]);
            acc[j][1] = fmaf(w, sv.y, acc[j][1]);
            acc[j][2] = fmaf(w, sv.z, acc[j][2]);
            acc[j][3] = fmaf(w, sv.w, acc[j][3]);
        }
    }
#pragma unroll
    for (int j = 0; j < 16; ++j) {
        int o = og * 16 + j;
        float bo = b_out[o];
        int oi = b * (CIN * HW) + o * HW + p0;
        float4 xv = *(const float4*)(x + oi);
        float4 o4;
        o4.x = xv.x + g * (acc[j][0] + bo);
        o4.y = xv.y + g * (acc[j][1] + bo);
        o4.z = xv.z + g * (acc[j][2] + bo);
        o4.w = xv.w + g * (acc[j][3] + bo);
        *(float4*)(out0 + oi) = o4;
    }
}

extern "C" void kernel_launch(void* const* d_in, const int* in_sizes, int n_in,
                              void* d_out, int out_size, void* d_ws, size_t ws_size,
                              hipStream_t stream) {
    const float* x       = (const float*)d_in[0];
    const float* prior   = (const float*)d_in[1];
    const float* W_in    = (const float*)d_in[2];
    const float* b_in    = (const float*)d_in[3];
    const float* W_out   = (const float*)d_in[4];
    const float* b_out   = (const float*)d_in[5];
    const float* W_delta = (const float*)d_in[6];
    const float* b_delta = (const float*)d_in[7];
    const float* W_B     = (const float*)d_in[8];
    const float* b_B     = (const float*)d_in[9];
    const float* lam     = (const float*)d_in[10];
    const float* alpha   = (const float*)d_in[11];
    const float* A       = (const float*)d_in[12];
    const float* gamma   = (const float*)d_in[13];

    float* out0 = (float*)d_out;                       // [8,64,128,128]
    float* out1 = (float*)d_out + NB * CIN * HW;       // prior_up [8,1,128,128]

    const size_t FIELD = (size_t)NB * HID * HW;        // 16,777,216 floats
    float* Abar  = (float*)d_ws;
    float* bbuf  = Abar + FIELD;
    float* sumb  = bbuf + FIELD;
    float* wcomp = sumb + FIELD;                       // 2*HID*CIN + 2*HID floats

    // L1: upsample (always) + weight-compose (always) + copy (gamma==0 only)
    head_kernel<<<dim3(4641), dim3(256), 0, stream>>>(
        x, prior, W_in, b_in, W_delta, b_delta, W_B, b_B, wcomp, out0, out1, gamma);
    // L2: fused feat/delta/B gate, K=64 from x directly
    gate_kernel<<<dim3(16, 8, NB), dim3(256), 0, stream>>>(
        x, out1, W_in, b_in, wcomp, lam, alpha, A, Abar, bbuf, gamma);
    // L3: both scans fused, single h+v sum output
    scan_sum_kernel<<<dim3(NB * HID), dim3(256), 0, stream>>>(Abar, bbuf, sumb, gamma);
    // L4: output conv + residual
    conv_out_kernel<<<dim3(16, 4, NB), dim3(256), 0, stream>>>(
        sumb, x, W_out, b_out, gamma, out0);
}

// Round 2
// 113.984 us; speedup vs baseline: 1.0037x; 1.0037x over previous
//
#include <hip/hip_runtime.h>
#include <math.h>

#define HID 128
#define CIN 64
#define NB 8
#define HD 128
#define WD 128
#define HW (HD*WD)   // 16384

// wcomp layout (floats, in ws 4th field):
//   [0, 24576)        wg[og=8][c=64][48]  : 48 = {W_in row | Wd' row | Wb' row} for 16 outs
//   [24576, 24704)    bd'[128]
//   [24704, 24832)    bb'[128]
//   [24832, 33024)    wout_t[c=128][o=64] : W_out transposed (c-major)
#define WG_OFF   0
#define BD_OFF   24576
#define BB_OFF   24704
#define WO_OFF   24832

// =================== L1: upsample + weight-compose + (gamma==0 only) copy ===================
__global__ __launch_bounds__(256, 2) void head_kernel(const float* __restrict__ x,
                                                      const float* __restrict__ prior,
                                                      const float* __restrict__ W_in,
                                                      const float* __restrict__ b_in,
                                                      const float* __restrict__ W_out,
                                                      const float* __restrict__ W_delta,
                                                      const float* __restrict__ b_delta,
                                                      const float* __restrict__ W_B,
                                                      const float* __restrict__ b_B,
                                                      float* __restrict__ wcomp,
                                                      float* __restrict__ out0,
                                                      float* __restrict__ out1,
                                                      const float* __restrict__ gamma_p) {
    int bid = blockIdx.x;
    if (bid < 512) {
        int idx = bid * 256 + threadIdx.x;                 // 512*256 = 131072 = 8*128*128
        int b = idx >> 14;
        int rem = idx & 16383;
        int i = rem >> 7, j = rem & 127;
        const float scale = 63.0f / 127.0f;
        float ys = i * scale;
        float xs = j * scale;
        int y0 = (int)floorf(ys); int y1 = min(y0 + 1, 63);
        int x0 = (int)floorf(xs); int x1 = min(x0 + 1, 63);
        float wy = ys - (float)y0, wx = xs - (float)x0;
        const float* p = prior + b * 4096;
        float v00 = p[y0 * 64 + x0], v01 = p[y0 * 64 + x1];
        float v10 = p[y1 * 64 + x0], v11 = p[y1 * 64 + x1];
        float r0 = v00 * (1.f - wy) + v10 * wy;
        float r1 = v01 * (1.f - wy) + v11 * wy;
        float v = r0 * (1.f - wx) + r1 * wx;
        v = fminf(fmaxf(v, -1.f), 1.f);
        out1[idx] = v;
        return;
    }
    if (bid < 544) {
        // per (o,c): Wd'[o][c] = sum_h W_delta[o][h] W_in[h][c]; interleave with W_in row
        int idx = (bid - 512) * 256 + threadIdx.x;         // [0, 8192) = HID*CIN
        int o = idx >> 6, c = idx & 63;
        float wd = 0.f, wb = 0.f;
        for (int h = 0; h < HID; ++h) {
            float wi = W_in[h * CIN + c];
            wd = fmaf(W_delta[o * HID + h], wi, wd);
            wb = fmaf(W_B[o * HID + h], wi, wb);
        }
        int og = o >> 4, j = o & 15;
        int base = WG_OFF + og * (CIN * 48) + c * 48;
        wcomp[base + j]      = W_in[o * CIN + c];
        wcomp[base + 16 + j] = wd;
        wcomp[base + 32 + j] = wb;
        return;
    }
    if (bid == 544) {
        int o = threadIdx.x;
        if (o < HID) {
            float sd = b_delta[o], sb = b_B[o];
            for (int h = 0; h < HID; ++h) {
                float bi = b_in[h];
                sd = fmaf(W_delta[o * HID + h], bi, sd);
                sb = fmaf(W_B[o * HID + h], bi, sb);
            }
            wcomp[BD_OFF + o] = sd;
            wcomp[BB_OFF + o] = sb;
        }
        return;
    }
    if (bid < 577) {
        // wout_t[c][o] = W_out[o][c]
        int idx = (bid - 545) * 256 + threadIdx.x;         // [0, 8192) = HID*CIN
        int c = idx >> 6, o = idx & 63;
        wcomp[WO_OFF + idx] = W_out[o * HID + c];
        return;
    }
    // ---- copy region: gamma!=0 => out0 fully written by hconv; skip ----
    if (gamma_p[0] != 0.f) return;
    int idx = ((bid - 577) * 256 + threadIdx.x) * 4;       // 4096 blocks cover 4,194,304 floats
    *(float4*)(out0 + idx) = *(const float4*)(x + idx);
    int idx2 = idx + 4194304;
    *(float4*)(out0 + idx2) = *(const float4*)(x + idx2);
}

// ======= L2: fused gate: feat/delta/B GEMMs (K=64 from x), weights via scalar loads =======
__global__ __launch_bounds__(256, 2) void gate_kernel(const float* __restrict__ x,
                                                      const float* __restrict__ pu,
                                                      const float* __restrict__ wcomp,
                                                      const float* __restrict__ b_in,
                                                      const float* __restrict__ lam_p,
                                                      const float* __restrict__ alpha_p,
                                                      const float* __restrict__ A,
                                                      float* __restrict__ Abar,
                                                      float* __restrict__ bbuf,
                                                      const float* __restrict__ gamma_p) {
    if (gamma_p[0] == 0.f) return;
    const float lam = lam_p[0], alpha = alpha_p[0];
    int bx = blockIdx.x;                                   // 16 spatial tiles of 1024 px
    int og = blockIdx.y;                                   // 8 groups of 16 channels
    int b  = blockIdx.z;
    int p0 = bx * 1024 + threadIdx.x * 4;
    const float* wg = wcomp + WG_OFF + og * (CIN * 48);    // uniform -> s_load

    float ai[16][4], ad[16][4], ab[16][4];
#pragma unroll
    for (int j = 0; j < 16; ++j)
#pragma unroll
        for (int k = 0; k < 4; ++k) { ai[j][k] = 0.f; ad[j][k] = 0.f; ab[j][k] = 0.f; }

    const float* xb = x + b * (CIN * HW) + p0;
    for (int c = 0; c < CIN; ++c) {
        float4 xv = *(const float4*)(xb + c * HW);
        const float* w = wg + c * 48;
#pragma unroll
        for (int j = 0; j < 16; ++j) {
            float wi = w[j];
            float wd = w[16 + j];
            float wb = w[32 + j];
            ai[j][0] = fmaf(wi, xv.x, ai[j][0]);
            ai[j][1] = fmaf(wi, xv.y, ai[j][1]);
            ai[j][2] = fmaf(wi, xv.z, ai[j][2]);
            ai[j][3] = fmaf(wi, xv.w, ai[j][3]);
            ad[j][0] = fmaf(wd, xv.x, ad[j][0]);
            ad[j][1] = fmaf(wd, xv.y, ad[j][1]);
            ad[j][2] = fmaf(wd, xv.z, ad[j][2]);
            ad[j][3] = fmaf(wd, xv.w, ad[j][3]);
            ab[j][0] = fmaf(wb, xv.x, ab[j][0]);
            ab[j][1] = fmaf(wb, xv.y, ab[j][1]);
            ab[j][2] = fmaf(wb, xv.z, ab[j][2]);
            ab[j][3] = fmaf(wb, xv.w, ab[j][3]);
        }
    }

    float4 pu4 = *(const float4*)(pu + b * HW + p0);
    float pus[4] = {pu4.x, pu4.y, pu4.z, pu4.w};
    int base = b * (HID * HW) + p0;
#pragma unroll
    for (int j = 0; j < 16; ++j) {
        int o = og * 16 + j;
        float bi = b_in[o];
        float bd = wcomp[BD_OFF + o];
        float bb2 = wcomp[BB_OFF + o];
        float nA = -expf(A[o]);
        float Ao[4], bo[4];
#pragma unroll
        for (int k = 0; k < 4; ++k) {
            float dv = ad[j][k] + bd + lam * pus[k];
            float d  = fmaxf(dv, 0.f) + log1pf(expf(-fabsf(dv)));   // softplus
            Ao[k] = expf(d * nA);
            float feat = ai[j][k] + bi;
            float Bk = (ab[j][k] + bb2) * (1.f + alpha * pus[k]);
            bo[k] = d * Bk * feat;
        }
        *(float4*)(Abar + base + o * HW) = make_float4(Ao[0], Ao[1], Ao[2], Ao[3]);
        *(float4*)(bbuf + base + o * HW) = make_float4(bo[0], bo[1], bo[2], bo[3]);
    }
}

// =================== L3a: vertical scan, thread-per-column, full occupancy ===================
__global__ __launch_bounds__(256) void vscan_kernel(const float* __restrict__ Abar,
                                                    const float* __restrict__ bbuf,
                                                    float* __restrict__ vsum,
                                                    const float* __restrict__ gamma_p) {
    if (gamma_p[0] == 0.f) return;
    int idx = blockIdx.x * 256 + threadIdx.x;              // [0,131072): (b*HID+c)*WD + col
    int base = (idx >> 7) * HW + (idx & 127);
    float P = 1.f, s = 0.f;
    for (int i = 0; i < HD; ++i) {
        int off = base + i * WD;
        float a  = Abar[off];
        float bv = bbuf[off];
        P *= a;
        s += bv / fmaxf(P, 1e-8f);
        vsum[off] = P * s;
    }
}

// ====== L3b+L4 fused: per (row,b): h-scan all 128 ch -> LDS sum, then out conv from LDS ======
__global__ __launch_bounds__(256, 2) void hconv_kernel(const float* __restrict__ Abar,
                                                       const float* __restrict__ bbuf,
                                                       const float* __restrict__ vsum,
                                                       const float* __restrict__ x,
                                                       const float* __restrict__ wcomp,
                                                       const float* __restrict__ b_out,
                                                       const float* __restrict__ gamma_p,
                                                       float* __restrict__ out0) {
    float g = gamma_p[0];
    if (g == 0.f) return;
    __shared__ float slds[HID][WD];                        // 64 KB: sum[c][px] for this row
    int row = blockIdx.x, b = blockIdx.y;
    int t = threadIdx.x, lane = t & 63, wv = t >> 6;
    const float* Ab = Abar + (size_t)b * HID * HW + row * WD;
    const float* Bb = bbuf + (size_t)b * HID * HW + row * WD;
    const float* Vb = vsum + (size_t)b * HID * HW + row * WD;
    // ---- h-phase: wave wv handles channels [wv*32, wv*32+32), shuffle scan per row ----
    for (int it = 0; it < 32; ++it) {
        int c = wv * 32 + it;
        int coff = c * HW + lane * 2;
        float2 a2 = *(const float2*)(Ab + coff);
        float2 b2 = *(const float2*)(Bb + coff);
        float pa = a2.x, pb = a2.x * a2.y;
        float Lp = pb;
#pragma unroll
        for (int off = 1; off < 64; off <<= 1) {
            float tt = __shfl_up(Lp, off, 64);
            if (lane >= off) Lp *= tt;
        }
        float ep = __shfl_up(Lp, 1, 64);
        if (lane == 0) ep = 1.f;
        float P0 = ep * pa, P1 = ep * pb;
        float q0 = b2.x / fmaxf(P0, 1e-8f);
        float q1 = b2.y / fmaxf(P1, 1e-8f);
        float s0 = q0, s1 = q0 + q1;
        float Ls = s1;
#pragma unroll
        for (int off = 1; off < 64; off <<= 1) {
            float tt = __shfl_up(Ls, off, 64);
            if (lane >= off) Ls += tt;
        }
        float es = __shfl_up(Ls, 1, 64);
        if (lane == 0) es = 0.f;
        float h0 = P0 * (es + s0), h1 = P1 * (es + s1);
        float2 v2 = *(const float2*)(Vb + coff);
        *(float2*)(&slds[c][lane * 2]) = make_float2(h0 + v2.x, h1 + v2.y);
    }
    __syncthreads();
    // ---- conv phase: wave wv owns out channels [wv*16, wv*16+16); lane owns 2 px ----
    int wvu = __builtin_amdgcn_readfirstlane(wv);
    const float* wt = wcomp + WO_OFF;                      // [c][64]
    float acc[16][2];
#pragma unroll
    for (int j = 0; j < 16; ++j) { acc[j][0] = 0.f; acc[j][1] = 0.f; }
    for (int c = 0; c < HID; ++c) {
        float2 sv = *(const float2*)(&slds[c][lane * 2]);
        const float* w = wt + c * 64 + wvu * 16;           // uniform -> s_load
#pragma unroll
        for (int j = 0; j < 16; ++j) {
            acc[j][0] = fmaf(w[j], sv.x, acc[j][0]);
            acc[j][1] = fmaf(w[j], sv.y, acc[j][1]);
        }
    }
#pragma unroll
    for (int j = 0; j < 16; ++j) {
        int o = wvu * 16 + j;
        float bo = b_out[o];
        int oi = b * (CIN * HW) + o * HW + row * WD + lane * 2;
        float2 xv = *(const float2*)(x + oi);
        float2 o2;
        o2.x = xv.x + g * (acc[j][0] + bo);
        o2.y = xv.y + g * (acc[j][1] + bo);
        *(float2*)(out0 + oi) = o2;
    }
}

extern "C" void kernel_launch(void* const* d_in, const int* in_sizes, int n_in,
                              void* d_out, int out_size, void* d_ws, size_t ws_size,
                              hipStream_t stream) {
    const float* x       = (const float*)d_in[0];
    const float* prior   = (const float*)d_in[1];
    const float* W_in    = (const float*)d_in[2];
    const float* b_in    = (const float*)d_in[3];
    const float* W_out   = (const float*)d_in[4];
    const float* b_out   = (const float*)d_in[5];
    const float* W_delta = (const float*)d_in[6];
    const float* b_delta = (const float*)d_in[7];
    const float* W_B     = (const float*)d_in[8];
    const float* b_B     = (const float*)d_in[9];
    const float* lam     = (const float*)d_in[10];
    const float* alpha   = (const float*)d_in[11];
    const float* A       = (const float*)d_in[12];
    const float* gamma   = (const float*)d_in[13];

    float* out0 = (float*)d_out;                       // [8,64,128,128]
    float* out1 = (float*)d_out + NB * CIN * HW;       // prior_up [8,1,128,128]

    const size_t FIELD = (size_t)NB * HID * HW;        // 16,777,216 floats
    float* Abar  = (float*)d_ws;
    float* bbuf  = Abar + FIELD;
    float* vsum  = bbuf + FIELD;
    float* wcomp = vsum + FIELD;                       // 33,024 floats used

    // L1: upsample (always) + weight compose/transpose (always) + copy (gamma==0 only)
    head_kernel<<<dim3(4673), dim3(256), 0, stream>>>(
        x, prior, W_in, b_in, W_out, W_delta, b_delta, W_B, b_B, wcomp, out0, out1, gamma);
    // L2: fused feat/delta/B gate, K=64 from x, scalar-load weights
    gate_kernel<<<dim3(16, 8, NB), dim3(256), 0, stream>>>(
        x, out1, wcomp, b_in, lam, alpha, A, Abar, bbuf, gamma);
    // L3a: vertical scan -> vsum
    vscan_kernel<<<dim3(512), dim3(256), 0, stream>>>(Abar, bbuf, vsum, gamma);
    // L3b+L4: h-scan + add vsum + output conv + residual, straight from LDS
    hconv_kernel<<<dim3(HD, NB), dim3(256), 0, stream>>>(
        Abar, bbuf, vsum, x, wcomp, b_out, gamma, out0);
}